// Round 20
// baseline (782.995 us; speedup 1.0000x reference)
//
#include <hip/hip_runtime.h>
#include <hip/hip_bf16.h>

// ---------- types ----------
typedef _Float16 h16;
typedef h16   h16x8 __attribute__((ext_vector_type(8)));
typedef h16   h16x4 __attribute__((ext_vector_type(4)));
typedef float f32x4 __attribute__((ext_vector_type(4)));

#define EMB 1024
#define ED4 4096L   // EMB*4 flattened feature dim

// ---------- async global->LDS (16B per lane, wave-uniform LDS base) ----------
__device__ __forceinline__ void gload_lds16(const void* g, void* l) {
    __builtin_amdgcn_global_load_lds(
        (__attribute__((address_space(1))) void*)g,
        (__attribute__((address_space(3))) void*)l,
        16, 0, 0);
}

// ---------- build effective block weight (device helper) ----------
// M[o*4+q][i*4+c] = s(q,c)*W[q^c][o][i]; thread handles an i-pair.
__device__ __forceinline__ void build_m_body(int t, const float* __restrict__ W, h16* __restrict__ M) {
    int i2 = t & 511;
    int n  = t >> 9;
    int o = n >> 2, q = n & 3;
    unsigned packed = 0xEu | (0x8u << 4) | (0x2u << 8) | (0x4u << 12);
    unsigned sm = (packed >> (q * 4)) & 0xFu;
    h16x8 out;
#pragma unroll
    for (int c = 0; c < 4; ++c) {
        int d = q ^ c;
        const float* wp = &W[((long)d * EMB + o) * EMB + i2 * 2];
        float s = ((sm >> c) & 1u) ? -1.0f : 1.0f;
        out[c]     = (h16)(s * wp[0]);
        out[4 + c] = (h16)(s * wp[1]);
    }
    *(h16x8*)&M[(long)n * ED4 + i2 * 8] = out;
}

__device__ __forceinline__ void convert_body(long t, const float* __restrict__ in, h16* __restrict__ out) {
    long i = t * 8;
    float4 v0 = *(const float4*)(in + i);
    float4 v1 = *(const float4*)(in + i + 4);
    h16x8 o;
    o[0] = (h16)v0.x; o[1] = (h16)v0.y; o[2] = (h16)v0.z; o[3] = (h16)v0.w;
    o[4] = (h16)v1.x; o[5] = (h16)v1.y; o[6] = (h16)v1.z; o[7] = (h16)v1.w;
    *(h16x8*)(out + i) = o;
}

// ---------- fused prep: blocks [0,8192) convert x, [8192,16384) build M ----------
__global__ __launch_bounds__(256) void k_prep(const float* __restrict__ x_in, h16* __restrict__ x_out,
                                              const float* __restrict__ W, h16* __restrict__ M) {
    if (blockIdx.x < 8192)
        convert_body((long)blockIdx.x * 256 + threadIdx.x, x_in, x_out);
    else
        build_m_body((blockIdx.x - 8192) * 256 + threadIdx.x, W, M);
}

// ---------- standalone build (output projection) ----------
__global__ __launch_bounds__(256) void k_build_m(const float* __restrict__ W, h16* __restrict__ M) {
    build_m_body(blockIdx.x * 256 + threadIdx.x, W, M);
}

// =====================================================================
// 256x256-tile, BK=64, 2-phase GEMM — r20 refinements on r18 green:
//  (1) STAGE issued at TOP of each phase (global loads in flight during
//      the phase's ds_reads+MFMA). Ledger unchanged: stages are gated by
//      the PREVIOUS phase's end-barrier; phA stages hit the other buffer,
//      phB stages hit regions disjoint from its A1 reads.
//  (2) phase-B counted vmcnt moved AFTER the MFMAs (still before the
//      end-BAR, which is all that gates tile t+1's reads) — the 32 MFMAs
//      now run while the in-flight loads land instead of stalling first.
// vmcnt math unchanged: per tile phA issues 4 loads, phB 4; vmcnt(4)
// leaves only (t+2).A0/B0 in flight -> tile t+1 fully landed. vmcnt(0)
// at t >= nt-2. Balanced read split: phA 16 reads, phB 8.
// Generalized: projections (nt=64), scores (nt=4, z=64), PV (nt=16, z=64).
// VT=true: V-projection epilogue writes Vt[(b*16+h)][f][t] directly.
// =====================================================================
#define BAR() __builtin_amdgcn_s_barrier()
#define STAGE(matv, basev, row0v, ldv, tt, hh) do { \
    const h16* _src = (basev) + ((row0v) + (hh) * 128L) * (ldv) + (long)(tt) * 64 + scol; \
    h16* _dst = &lds[(((tt) & 1) << 15) + (matv) * 16384 + (hh) * 8192 + w * 512]; \
    gload_lds16(_src, _dst); \
    gload_lds16(_src + 64 * (long)(ldv), _dst + 4096); \
} while (0)
#define LDA_(mh, m, ks) (*(const h16x8*)&lds[cb + (mh) * 8192 + (wm * 64 + (m) * 16 + fr) * 64 + ((((ks) * 4 + kq) ^ fr7) << 3)])
#define LDB_(nh, n, ks) (*(const h16x8*)&lds[cb + 16384 + (nh) * 8192 + (wn * 32 + (n) * 16 + fr) * 64 + ((((ks) * 4 + kq) ^ fr7) << 3)])
#define MFMA_Q(MH, NH, BF) do { \
    __builtin_amdgcn_s_setprio(1); \
    _Pragma("unroll") \
    for (int m = 0; m < 4; ++m) \
        _Pragma("unroll") \
        for (int n = 0; n < 2; ++n) { \
            acc[MH][NH][m][n] = __builtin_amdgcn_mfma_f32_16x16x32_f16(af[m][0], BF[n][0], acc[MH][NH][m][n], 0, 0, 0); \
            acc[MH][NH][m][n] = __builtin_amdgcn_mfma_f32_16x16x32_f16(af[m][1], BF[n][1], acc[MH][NH][m][n], 0, 0, 0); \
        } \
    __builtin_amdgcn_s_setprio(0); \
} while (0)

template <typename OUT_T, bool VT, bool HAS_BIAS>
__global__ __launch_bounds__(512, 2) void k_gemm256(
    const h16* __restrict__ A, const h16* __restrict__ B,
    OUT_T* __restrict__ C, const float* __restrict__ bias,
    int lda, int ldb, int ldc,
    long sAb, long sAh, long sBb, long sBh, long sCb, long sCh,
    float alpha, int nt)
{
    __shared__ __align__(16) h16 lds[65536];   // 128 KiB

    const int tid = threadIdx.x;
    const int w  = tid >> 6, l = tid & 63;
    const int wm = w >> 2, wn = w & 3;          // wave grid 2x4 within each quadrant
    const int fr = l & 15, fr7 = l & 7, kq = l >> 4;

    const int z = blockIdx.z, zb = z >> 4, zh = z & 15;
    const h16* Ab = A + zb * sAb + zh * sAh;
    const h16* Bb = B + zb * sBb + zh * sBh;

    // staging: thread covers 16B; srow in [0,64) per gload, swizzled col
    const int srow = w * 8 + (l >> 3);
    const int scol = ((l & 7) ^ ((l >> 3) & 7)) << 3;
    const long arow0 = (long)blockIdx.x * 256 + srow;
    const long brow0 = (long)blockIdx.y * 256 + srow;

    f32x4 acc[2][2][4][2] = {};   // [mh][nh][m][n]

    // prologue: 0.A0 0.B0 0.A1 0.B1 1.A0 1.B0 (12 loads); vmcnt(4) -> tile0 landed
    STAGE(0, Ab, arow0, lda, 0, 0);
    STAGE(1, Bb, brow0, ldb, 0, 0);
    STAGE(0, Ab, arow0, lda, 0, 1);
    STAGE(1, Bb, brow0, ldb, 0, 1);
    STAGE(0, Ab, arow0, lda, 1, 0);
    STAGE(1, Bb, brow0, ldb, 1, 0);
    asm volatile("s_waitcnt vmcnt(4)" ::: "memory");
    __builtin_amdgcn_sched_barrier(0);
    BAR();

    for (int t = 0; t < nt; ++t) {
        const int cb = (t & 1) << 15;
        h16x8 af[4][2], b0[2][2], b1[2][2];

        // ---- phase A: stage (t+1).A1,B1 first; read A0,B0,B1; MFMA (0,*) ----
        if (t + 1 < nt) {
            STAGE(0, Ab, arow0, lda, t + 1, 1);
            STAGE(1, Bb, brow0, ldb, t + 1, 1);
        }
#pragma unroll
        for (int m = 0; m < 4; ++m) { af[m][0] = LDA_(0, m, 0); af[m][1] = LDA_(0, m, 1); }
#pragma unroll
        for (int n = 0; n < 2; ++n) { b0[n][0] = LDB_(0, n, 0); b0[n][1] = LDB_(0, n, 1); }
#pragma unroll
        for (int n = 0; n < 2; ++n) { b1[n][0] = LDB_(1, n, 0); b1[n][1] = LDB_(1, n, 1); }
        MFMA_Q(0, 0, b0);
        MFMA_Q(0, 1, b1);
        BAR();

        // ---- phase B: stage (t+2).A0,B0 first; read A1; MFMA (1,*); drain ----
        if (t + 2 < nt) {
            STAGE(0, Ab, arow0, lda, t + 2, 0);
            STAGE(1, Bb, brow0, ldb, t + 2, 0);
        }
#pragma unroll
        for (int m = 0; m < 4; ++m) { af[m][0] = LDA_(1, m, 0); af[m][1] = LDA_(1, m, 1); }
        MFMA_Q(1, 0, b0);
        MFMA_Q(1, 1, b1);
        if (t < nt - 2) { asm volatile("s_waitcnt vmcnt(4)" ::: "memory"); }
        else            { asm volatile("s_waitcnt vmcnt(0)" ::: "memory"); }
        __builtin_amdgcn_sched_barrier(0);
        BAR();
    }

    // epilogue: row = bx*256 + mh*128 + wm*64 + m*16 + kq*4 + j
    //           col = by*256 + nh*128 + wn*32 + n*16 + fr
    OUT_T* Cb = C + zb * sCb + zh * sCh;
    const long row00 = (long)blockIdx.x * 256 + wm * 64 + kq * 4;
    const int  col00 = (int)blockIdx.y * 256 + wn * 32 + fr;
#pragma unroll
    for (int mh = 0; mh < 2; ++mh)
#pragma unroll
        for (int nh = 0; nh < 2; ++nh)
#pragma unroll
            for (int n = 0; n < 2; ++n) {
                const int col = col00 + nh * 128 + n * 16;
                const float bv = HAS_BIAS ? bias[col] : 0.0f;
#pragma unroll
                for (int m = 0; m < 4; ++m) {
                    const long r0 = row00 + mh * 128 + m * 16;
                    if constexpr (VT) {
                        // Vt[(r>>10)*16 + (col>>8)][col&255][r&1023], r0 % 4 == 0
                        h16x4 o;
#pragma unroll
                        for (int j = 0; j < 4; ++j) o[j] = (h16)(acc[mh][nh][m][n][j] * alpha + bv);
                        const long zidx = (r0 >> 10) * 16 + (col >> 8);
                        *(h16x4*)((h16*)Cb + zidx * 262144L + (long)(col & 255) * 1024 + (r0 & 1023)) = o;
                    } else {
#pragma unroll
                        for (int j = 0; j < 4; ++j)
                            Cb[(r0 + j) * (long)ldc + col] = (OUT_T)(acc[mh][nh][m][n][j] * alpha + bv);
                    }
                }
            }
}

// ---------- row softmax: one WAVE per row, 4 rows/block, no LDS ----------
__global__ __launch_bounds__(256) void k_softmax(h16* __restrict__ S) {
    const int w = threadIdx.x >> 6, l = threadIdx.x & 63;
    h16* p = S + ((long)blockIdx.x * 4 + w) * 1024 + l * 16;
    h16x8 a = *(const h16x8*)p;
    h16x8 b = *(const h16x8*)(p + 8);
    float x[16];
#pragma unroll
    for (int j = 0; j < 8; ++j) { x[j] = (float)a[j]; x[8 + j] = (float)b[j]; }
    float m = x[0];
#pragma unroll
    for (int j = 1; j < 16; ++j) m = fmaxf(m, x[j]);
#pragma unroll
    for (int off = 32; off; off >>= 1) m = fmaxf(m, __shfl_xor(m, off));
    float s = 0.0f;
#pragma unroll
    for (int j = 0; j < 16; ++j) { x[j] = __expf(x[j] - m); s += x[j]; }
#pragma unroll
    for (int off = 32; off; off >>= 1) s += __shfl_xor(s, off);
    const float inv = 1.0f / s;
#pragma unroll
    for (int j = 0; j < 8; ++j) { a[j] = (h16)(x[j] * inv); b[j] = (h16)(x[8 + j] * inv); }
    *(h16x8*)p = a;
    *(h16x8*)(p + 8) = b;
}

// ---------- launch ----------
extern "C" void kernel_launch(void* const* d_in, const int* in_sizes, int n_in,
                              void* d_out, int out_size, void* d_ws, size_t ws_size,
                              hipStream_t stream) {
    const float* q  = (const float*)d_in[0];
    const float* k  = (const float*)d_in[1];
    const float* v  = (const float*)d_in[2];
    const float* Wq = (const float*)d_in[3];
    const float* bq = (const float*)d_in[4];
    const float* Wk = (const float*)d_in[5];
    const float* bk = (const float*)d_in[6];
    const float* Wv = (const float*)d_in[7];
    const float* bv = (const float*)d_in[8];
    const float* Wo = (const float*)d_in[9];
    const float* bo = (const float*)d_in[10];
    float* out = (float*)d_out;

    // workspace: 256 MB exactly (proven budget; 320 MB faulted in r12).
    // S gets the full 128 MB [128,256); X and M aliased INSIDE S's range —
    // timeline-safe (X dead after V-projection; M rebuilt for Wo only
    // after PV consumed S).
    char* ws = (char*)d_ws;
    const long MB = 1024L * 1024;
    h16* Qb = (h16*)(ws + 0 * MB);
    h16* Kb = (h16*)(ws + 32 * MB);
    h16* Vt = (h16*)(ws + 64 * MB);    // Vt[64 z][256 f][1024 t]
    h16* AO = (h16*)(ws + 96 * MB);
    h16* S  = (h16*)(ws + 128 * MB);   // S[64 z][1024][1024] fp16 = 128 MB
    h16* M  = (h16*)(ws + 192 * MB);   // 32 MB, aliases S (timeline-safe)
    h16* X  = (h16*)(ws + 224 * MB);   // 32 MB, aliases S (timeline-safe)

    dim3 blk(256);
    dim3 g256(16, 16, 1);

    // Q projection: fused convert+build, then GEMM (serially reusing X, M)
    k_prep<<<16384, blk, 0, stream>>>(q, X, Wq, M);
    k_gemm256<h16, false, true><<<g256, 512, 0, stream>>>(
        X, M, Qb, bq, 4096, 4096, 4096, 0, 0, 0, 0, 0, 0, 1.0f, 64);

    // K projection
    k_prep<<<16384, blk, 0, stream>>>(k, X, Wk, M);
    k_gemm256<h16, false, true><<<g256, 512, 0, stream>>>(
        X, M, Kb, bk, 4096, 4096, 4096, 0, 0, 0, 0, 0, 0, 1.0f, 64);

    // V projection (epilogue writes transposed Vt directly)
    k_prep<<<16384, blk, 0, stream>>>(v, X, Wv, M);
    k_gemm256<h16, true, true><<<g256, 512, 0, stream>>>(
        X, M, Vt, bv, 4096, 4096, 4096, 0, 0, 0, 0, 0, 0, 1.0f, 64);

    // scores: S[z][1024][1024] = (Q_z K_z^T)/16, fp16 — z=64, 1024 WGs
    k_gemm256<h16, false, false><<<dim3(4, 4, 64), 512, 0, stream>>>(
        Qb, Kb, S, nullptr,
        4096, 4096, 1024,
        1024L * 4096, 256,                    // A: zb (batch), zh (head) strides
        1024L * 4096, 256,                    // B
        16L * 1024 * 1024, 1024L * 1024,      // C
        0.0625f, 4);

    // softmax rows in place (fp16): 65536 rows, 4 rows/block (wave-per-row)
    k_softmax<<<16384, blk, 0, stream>>>(S);

    // attn out: AO[b*1024+t][h*256+f] = P_z . Vt_z^T — z=64, 256 WGs (full machine)
    k_gemm256<h16, false, false><<<dim3(4, 1, 64), 512, 0, stream>>>(
        S, Vt, AO, nullptr,
        1024, 1024, 4096,
        16L * 1024 * 1024, 1024L * 1024,      // A: zb, zh strides (P)
        16L * 262144, 262144,                 // B: Vt
        1024L * 4096, 256,                    // C: AO
        1.0f, 16);

    // output projection: out = AO . Mo^T + bo (fp32 out)
    k_build_m<<<8192, blk, 0, stream>>>(Wo, M);
    k_gemm256<float, false, true><<<g256, 512, 0, stream>>>(
        AO, M, out, bo, 4096, 4096, 4096, 0, 0, 0, 0, 0, 0, 1.0f, 64);
}

// Round 21
// 760.296 us; speedup vs baseline: 1.0299x; 1.0299x over previous
//
#include <hip/hip_runtime.h>
#include <hip/hip_bf16.h>

// ---------- types ----------
typedef _Float16 h16;
typedef h16   h16x8 __attribute__((ext_vector_type(8)));
typedef h16   h16x4 __attribute__((ext_vector_type(4)));
typedef float f32x4 __attribute__((ext_vector_type(4)));

#define EMB 1024
#define ED4 4096L   // EMB*4 flattened feature dim

// ---------- async global->LDS (16B per lane, wave-uniform LDS base) ----------
__device__ __forceinline__ void gload_lds16(const void* g, void* l) {
    __builtin_amdgcn_global_load_lds(
        (__attribute__((address_space(1))) void*)g,
        (__attribute__((address_space(3))) void*)l,
        16, 0, 0);
}

// ---------- build effective block weight (device helper) ----------
// M[o*4+q][i*4+c] = s(q,c)*W[q^c][o][i]; thread handles an i-pair.
__device__ __forceinline__ void build_m_body(int t, const float* __restrict__ W, h16* __restrict__ M) {
    int i2 = t & 511;
    int n  = t >> 9;
    int o = n >> 2, q = n & 3;
    unsigned packed = 0xEu | (0x8u << 4) | (0x2u << 8) | (0x4u << 12);
    unsigned sm = (packed >> (q * 4)) & 0xFu;
    h16x8 out;
#pragma unroll
    for (int c = 0; c < 4; ++c) {
        int d = q ^ c;
        const float* wp = &W[((long)d * EMB + o) * EMB + i2 * 2];
        float s = ((sm >> c) & 1u) ? -1.0f : 1.0f;
        out[c]     = (h16)(s * wp[0]);
        out[4 + c] = (h16)(s * wp[1]);
    }
    *(h16x8*)&M[(long)n * ED4 + i2 * 8] = out;
}

__device__ __forceinline__ void convert_body(long t, const float* __restrict__ in, h16* __restrict__ out) {
    long i = t * 8;
    float4 v0 = *(const float4*)(in + i);
    float4 v1 = *(const float4*)(in + i + 4);
    h16x8 o;
    o[0] = (h16)v0.x; o[1] = (h16)v0.y; o[2] = (h16)v0.z; o[3] = (h16)v0.w;
    o[4] = (h16)v1.x; o[5] = (h16)v1.y; o[6] = (h16)v1.z; o[7] = (h16)v1.w;
    *(h16x8*)(out + i) = o;
}

// ---------- fused prep: blocks [0,8192) convert x, [8192,16384) build M ----------
__global__ __launch_bounds__(256) void k_prep(const float* __restrict__ x_in, h16* __restrict__ x_out,
                                              const float* __restrict__ W, h16* __restrict__ M) {
    if (blockIdx.x < 8192)
        convert_body((long)blockIdx.x * 256 + threadIdx.x, x_in, x_out);
    else
        build_m_body((blockIdx.x - 8192) * 256 + threadIdx.x, W, M);
}

// ---------- standalone build (output projection) ----------
__global__ __launch_bounds__(256) void k_build_m(const float* __restrict__ W, h16* __restrict__ M) {
    build_m_body(blockIdx.x * 256 + threadIdx.x, W, M);
}

// =====================================================================
// 256x256-tile, BK=64, 2-phase GEMM — r21: EXACT r18/r19 green inner
// loop restored (r20's stage-at-top + vmcnt-after-MFMA both regressed:
// 124 -> 133 us; stage-first delayed the ds_read->MFMA chain and the
// late vmcnt blocked the compiler's drain/MFMA overlap). Balanced split:
// phA reads A0,B0,B1 (16) then stages (t+1).A1,B1; phB reads A1 (8),
// stages (t+2).A0,B0, counted vmcnt(4) BEFORE the MFMAs. Ledger and
// vmcnt ladder as r13/r14/r16 green (6 schedule variants tested; this
// is the empirical optimum of the structure).
// Generalized: projections (nt=64), scores (nt=4, z=64), PV (nt=16, z=64).
// VT=true: V-projection epilogue writes Vt[(b*16+h)][f][t] directly.
// =====================================================================
#define BAR() __builtin_amdgcn_s_barrier()
#define STAGE(matv, basev, row0v, ldv, tt, hh) do { \
    const h16* _src = (basev) + ((row0v) + (hh) * 128L) * (ldv) + (long)(tt) * 64 + scol; \
    h16* _dst = &lds[(((tt) & 1) << 15) + (matv) * 16384 + (hh) * 8192 + w * 512]; \
    gload_lds16(_src, _dst); \
    gload_lds16(_src + 64 * (long)(ldv), _dst + 4096); \
} while (0)
#define LDA_(mh, m, ks) (*(const h16x8*)&lds[cb + (mh) * 8192 + (wm * 64 + (m) * 16 + fr) * 64 + ((((ks) * 4 + kq) ^ fr7) << 3)])
#define LDB_(nh, n, ks) (*(const h16x8*)&lds[cb + 16384 + (nh) * 8192 + (wn * 32 + (n) * 16 + fr) * 64 + ((((ks) * 4 + kq) ^ fr7) << 3)])
#define MFMA_Q(MH, NH, BF) do { \
    __builtin_amdgcn_s_setprio(1); \
    _Pragma("unroll") \
    for (int m = 0; m < 4; ++m) \
        _Pragma("unroll") \
        for (int n = 0; n < 2; ++n) { \
            acc[MH][NH][m][n] = __builtin_amdgcn_mfma_f32_16x16x32_f16(af[m][0], BF[n][0], acc[MH][NH][m][n], 0, 0, 0); \
            acc[MH][NH][m][n] = __builtin_amdgcn_mfma_f32_16x16x32_f16(af[m][1], BF[n][1], acc[MH][NH][m][n], 0, 0, 0); \
        } \
    __builtin_amdgcn_s_setprio(0); \
} while (0)

template <typename OUT_T, bool VT, bool HAS_BIAS>
__global__ __launch_bounds__(512, 2) void k_gemm256(
    const h16* __restrict__ A, const h16* __restrict__ B,
    OUT_T* __restrict__ C, const float* __restrict__ bias,
    int lda, int ldb, int ldc,
    long sAb, long sAh, long sBb, long sBh, long sCb, long sCh,
    float alpha, int nt)
{
    __shared__ __align__(16) h16 lds[65536];   // 128 KiB

    const int tid = threadIdx.x;
    const int w  = tid >> 6, l = tid & 63;
    const int wm = w >> 2, wn = w & 3;          // wave grid 2x4 within each quadrant
    const int fr = l & 15, fr7 = l & 7, kq = l >> 4;

    const int z = blockIdx.z, zb = z >> 4, zh = z & 15;
    const h16* Ab = A + zb * sAb + zh * sAh;
    const h16* Bb = B + zb * sBb + zh * sBh;

    // staging: thread covers 16B; srow in [0,64) per gload, swizzled col
    const int srow = w * 8 + (l >> 3);
    const int scol = ((l & 7) ^ ((l >> 3) & 7)) << 3;
    const long arow0 = (long)blockIdx.x * 256 + srow;
    const long brow0 = (long)blockIdx.y * 256 + srow;

    f32x4 acc[2][2][4][2] = {};   // [mh][nh][m][n]

    // prologue: 0.A0 0.B0 0.A1 0.B1 1.A0 1.B0 (12 loads); vmcnt(4) -> tile0 landed
    STAGE(0, Ab, arow0, lda, 0, 0);
    STAGE(1, Bb, brow0, ldb, 0, 0);
    STAGE(0, Ab, arow0, lda, 0, 1);
    STAGE(1, Bb, brow0, ldb, 0, 1);
    STAGE(0, Ab, arow0, lda, 1, 0);
    STAGE(1, Bb, brow0, ldb, 1, 0);
    asm volatile("s_waitcnt vmcnt(4)" ::: "memory");
    __builtin_amdgcn_sched_barrier(0);
    BAR();

    for (int t = 0; t < nt; ++t) {
        const int cb = (t & 1) << 15;
        h16x8 af[4][2], b0[2][2], b1[2][2];

        // ---- phase A: quadrants (0,0)+(0,1) — read A0,B0,B1; stage (t+1).A1,B1 ----
#pragma unroll
        for (int m = 0; m < 4; ++m) { af[m][0] = LDA_(0, m, 0); af[m][1] = LDA_(0, m, 1); }
#pragma unroll
        for (int n = 0; n < 2; ++n) { b0[n][0] = LDB_(0, n, 0); b0[n][1] = LDB_(0, n, 1); }
#pragma unroll
        for (int n = 0; n < 2; ++n) { b1[n][0] = LDB_(1, n, 0); b1[n][1] = LDB_(1, n, 1); }
        if (t + 1 < nt) {
            STAGE(0, Ab, arow0, lda, t + 1, 1);
            STAGE(1, Bb, brow0, ldb, t + 1, 1);
        }
        MFMA_Q(0, 0, b0);
        MFMA_Q(0, 1, b1);
        BAR();

        // ---- phase B: quadrants (1,0)+(1,1) — read A1; stage (t+2).A0,B0; drain ----
#pragma unroll
        for (int m = 0; m < 4; ++m) { af[m][0] = LDA_(1, m, 0); af[m][1] = LDA_(1, m, 1); }
        if (t + 2 < nt) {
            STAGE(0, Ab, arow0, lda, t + 2, 0);
            STAGE(1, Bb, brow0, ldb, t + 2, 0);
        }
        if (t < nt - 2) { asm volatile("s_waitcnt vmcnt(4)" ::: "memory"); }
        else            { asm volatile("s_waitcnt vmcnt(0)" ::: "memory"); }
        __builtin_amdgcn_sched_barrier(0);
        MFMA_Q(1, 0, b0);
        MFMA_Q(1, 1, b1);
        BAR();
    }

    // epilogue: row = bx*256 + mh*128 + wm*64 + m*16 + kq*4 + j
    //           col = by*256 + nh*128 + wn*32 + n*16 + fr
    OUT_T* Cb = C + zb * sCb + zh * sCh;
    const long row00 = (long)blockIdx.x * 256 + wm * 64 + kq * 4;
    const int  col00 = (int)blockIdx.y * 256 + wn * 32 + fr;
#pragma unroll
    for (int mh = 0; mh < 2; ++mh)
#pragma unroll
        for (int nh = 0; nh < 2; ++nh)
#pragma unroll
            for (int n = 0; n < 2; ++n) {
                const int col = col00 + nh * 128 + n * 16;
                const float bv = HAS_BIAS ? bias[col] : 0.0f;
#pragma unroll
                for (int m = 0; m < 4; ++m) {
                    const long r0 = row00 + mh * 128 + m * 16;
                    if constexpr (VT) {
                        // Vt[(r>>10)*16 + (col>>8)][col&255][r&1023], r0 % 4 == 0
                        h16x4 o;
#pragma unroll
                        for (int j = 0; j < 4; ++j) o[j] = (h16)(acc[mh][nh][m][n][j] * alpha + bv);
                        const long zidx = (r0 >> 10) * 16 + (col >> 8);
                        *(h16x4*)((h16*)Cb + zidx * 262144L + (long)(col & 255) * 1024 + (r0 & 1023)) = o;
                    } else {
#pragma unroll
                        for (int j = 0; j < 4; ++j)
                            Cb[(r0 + j) * (long)ldc + col] = (OUT_T)(acc[mh][nh][m][n][j] * alpha + bv);
                    }
                }
            }
}

// ---------- row softmax: one WAVE per row, 4 rows/block, no LDS ----------
__global__ __launch_bounds__(256) void k_softmax(h16* __restrict__ S) {
    const int w = threadIdx.x >> 6, l = threadIdx.x & 63;
    h16* p = S + ((long)blockIdx.x * 4 + w) * 1024 + l * 16;
    h16x8 a = *(const h16x8*)p;
    h16x8 b = *(const h16x8*)(p + 8);
    float x[16];
#pragma unroll
    for (int j = 0; j < 8; ++j) { x[j] = (float)a[j]; x[8 + j] = (float)b[j]; }
    float m = x[0];
#pragma unroll
    for (int j = 1; j < 16; ++j) m = fmaxf(m, x[j]);
#pragma unroll
    for (int off = 32; off; off >>= 1) m = fmaxf(m, __shfl_xor(m, off));
    float s = 0.0f;
#pragma unroll
    for (int j = 0; j < 16; ++j) { x[j] = __expf(x[j] - m); s += x[j]; }
#pragma unroll
    for (int off = 32; off; off >>= 1) s += __shfl_xor(s, off);
    const float inv = 1.0f / s;
#pragma unroll
    for (int j = 0; j < 8; ++j) { a[j] = (h16)(x[j] * inv); b[j] = (h16)(x[8 + j] * inv); }
    *(h16x8*)p = a;
    *(h16x8*)(p + 8) = b;
}

// ---------- launch ----------
extern "C" void kernel_launch(void* const* d_in, const int* in_sizes, int n_in,
                              void* d_out, int out_size, void* d_ws, size_t ws_size,
                              hipStream_t stream) {
    const float* q  = (const float*)d_in[0];
    const float* k  = (const float*)d_in[1];
    const float* v  = (const float*)d_in[2];
    const float* Wq = (const float*)d_in[3];
    const float* bq = (const float*)d_in[4];
    const float* Wk = (const float*)d_in[5];
    const float* bk = (const float*)d_in[6];
    const float* Wv = (const float*)d_in[7];
    const float* bv = (const float*)d_in[8];
    const float* Wo = (const float*)d_in[9];
    const float* bo = (const float*)d_in[10];
    float* out = (float*)d_out;

    // workspace: 256 MB exactly (proven budget; 320 MB faulted in r12).
    // S gets the full 128 MB [128,256); X and M aliased INSIDE S's range —
    // timeline-safe (X dead after V-projection; M rebuilt for Wo only
    // after PV consumed S).
    char* ws = (char*)d_ws;
    const long MB = 1024L * 1024;
    h16* Qb = (h16*)(ws + 0 * MB);
    h16* Kb = (h16*)(ws + 32 * MB);
    h16* Vt = (h16*)(ws + 64 * MB);    // Vt[64 z][256 f][1024 t]
    h16* AO = (h16*)(ws + 96 * MB);
    h16* S  = (h16*)(ws + 128 * MB);   // S[64 z][1024][1024] fp16 = 128 MB
    h16* M  = (h16*)(ws + 192 * MB);   // 32 MB, aliases S (timeline-safe)
    h16* X  = (h16*)(ws + 224 * MB);   // 32 MB, aliases S (timeline-safe)

    dim3 blk(256);
    dim3 g256(16, 16, 1);

    // Q projection: fused convert+build, then GEMM (serially reusing X, M)
    k_prep<<<16384, blk, 0, stream>>>(q, X, Wq, M);
    k_gemm256<h16, false, true><<<g256, 512, 0, stream>>>(
        X, M, Qb, bq, 4096, 4096, 4096, 0, 0, 0, 0, 0, 0, 1.0f, 64);

    // K projection
    k_prep<<<16384, blk, 0, stream>>>(k, X, Wk, M);
    k_gemm256<h16, false, true><<<g256, 512, 0, stream>>>(
        X, M, Kb, bk, 4096, 4096, 4096, 0, 0, 0, 0, 0, 0, 1.0f, 64);

    // V projection (epilogue writes transposed Vt directly)
    k_prep<<<16384, blk, 0, stream>>>(v, X, Wv, M);
    k_gemm256<h16, true, true><<<g256, 512, 0, stream>>>(
        X, M, Vt, bv, 4096, 4096, 4096, 0, 0, 0, 0, 0, 0, 1.0f, 64);

    // scores: S[z][1024][1024] = (Q_z K_z^T)/16, fp16 — z=64, 1024 WGs
    k_gemm256<h16, false, false><<<dim3(4, 4, 64), 512, 0, stream>>>(
        Qb, Kb, S, nullptr,
        4096, 4096, 1024,
        1024L * 4096, 256,                    // A: zb (batch), zh (head) strides
        1024L * 4096, 256,                    // B
        16L * 1024 * 1024, 1024L * 1024,      // C
        0.0625f, 4);

    // softmax rows in place (fp16): 65536 rows, 4 rows/block (wave-per-row)
    k_softmax<<<16384, blk, 0, stream>>>(S);

    // attn out: AO[b*1024+t][h*256+f] = P_z . Vt_z^T — z=64, 256 WGs (full machine)
    k_gemm256<h16, false, false><<<dim3(4, 1, 64), 512, 0, stream>>>(
        S, Vt, AO, nullptr,
        1024, 1024, 4096,
        16L * 1024 * 1024, 1024L * 1024,      // A: zb, zh strides (P)
        16L * 262144, 262144,                 // B: Vt
        1024L * 4096, 256,                    // C: AO
        1.0f, 16);

    // output projection: out = AO . Mo^T + bo (fp32 out)
    k_build_m<<<8192, blk, 0, stream>>>(Wo, M);
    k_gemm256<float, false, true><<<g256, 512, 0, stream>>>(
        AO, M, out, bo, 4096, 4096, 4096, 0, 0, 0, 0, 0, 0, 1.0f, 64);
}